// Round 18
// baseline (361.547 us; speedup 1.0000x reference)
//
#include <hip/hip_runtime.h>
#include <stdint.h>

typedef unsigned short u16;
typedef __attribute__((ext_vector_type(8))) short short8;   // 8 x bf16 (4 VGPRs)
typedef __attribute__((ext_vector_type(4))) short short4v;  // 4 x bf16 (8B)
typedef __attribute__((ext_vector_type(4))) float f32x4;
typedef __attribute__((ext_vector_type(16))) float f32x16;

__device__ __forceinline__ u16 f2b(float f){
  union { float f; unsigned u; } x; x.f = f;
  unsigned r = x.u + 0x7FFFu + ((x.u >> 16) & 1u);  // RNE
  return (u16)(r >> 16);
}
__device__ __forceinline__ float b2f(u16 u){
  return __uint_as_float(((unsigned)u) << 16);
}

__device__ __forceinline__ unsigned cvtpk_bf16(float lo, float hi){
  unsigned r;
  asm("v_cvt_pk_bf16_f32 %0, %1, %2" : "=v"(r) : "v"(lo), "v"(hi));
  return r;
}

__device__ __forceinline__ void gload_lds16(const void* g, void* l){
  __builtin_amdgcn_global_load_lds(
      (const __attribute__((address_space(1))) unsigned int*)g,
      (__attribute__((address_space(3))) unsigned int*)l, 16, 0, 0);
}

// -------- all weight transposes in one kernel: 704 tile-jobs ----------------------------
__global__ void __launch_bounds__(256) transpose_all(const float* __restrict__ wq,
                                                     const float* __restrict__ wk,
                                                     const float* __restrict__ wv,
                                                     const float* __restrict__ w1,
                                                     const float* __restrict__ w2,
                                                     u16* __restrict__ wqkvT,
                                                     u16* __restrict__ w1T,
                                                     u16* __restrict__ w2T){
  __shared__ float sm[32][33];
  int id = blockIdx.x;
  const float* in; u16* out; int K, N, kx, ny;
  if (id < 192){
    int j = id >> 6, r = id & 63;
    in = (j==0) ? wq : (j==1) ? wk : wv;
    out = wqkvT + (size_t)j*65536; K = 256; N = 256; kx = r>>3; ny = r&7;
  } else if (id < 448){
    int r = id - 192; in = w1; out = w1T; K = 256; N = 1024; kx = r&7; ny = r>>3;
  } else {
    int r = id - 448; in = w2; out = w2T; K = 1024; N = 256; kx = r>>3; ny = r&7;
  }
  int k0 = kx*32, n0 = ny*32;
  int t = threadIdx.x; int tr = t>>5, tc = t&31;   // 8 x 32
  #pragma unroll
  for (int p=0;p<4;p++) sm[p*8+tr][tc] = in[(size_t)(k0+p*8+tr)*N + n0+tc];
  __syncthreads();
  #pragma unroll
  for (int p=0;p<4;p++) out[(size_t)(n0+p*8+tr)*K + k0+tc] = f2b(sm[tc][p*8+tr]);
}

// ------- LayerNorm, wave-per-row: 4 rows/block, 4 elems/lane, shuffle-only reduce --------
__global__ void __launch_bounds__(256) ln_kernel(const float* __restrict__ in,
                                                 const float* __restrict__ g,
                                                 const float* __restrict__ bb,
                                                 u16* __restrict__ outB){
  int w = threadIdx.x >> 6, lane = threadIdx.x & 63;
  int row = blockIdx.x*4 + w;
  size_t base = (size_t)row*256 + lane*4;
  float4 v = *(const float4*)(in + base);
  float s = v.x + v.y + v.z + v.w;
  #pragma unroll
  for (int mk=1; mk<64; mk<<=1) s += __shfl_xor(s, mk);
  float mean = s * (1.0f/256.0f);
  float d0 = v.x-mean, d1 = v.y-mean, d2 = v.z-mean, d3 = v.w-mean;
  float q = d0*d0 + d1*d1 + d2*d2 + d3*d3;
  #pragma unroll
  for (int mk=1; mk<64; mk<<=1) q += __shfl_xor(q, mk);
  float rstd = rsqrtf(q * (1.0f/256.0f) + 1e-5f);
  float4 gg = *(const float4*)(g + lane*4);
  float4 be = *(const float4*)(bb + lane*4);
  short4v o;
  o[0] = (short)f2b(d0*rstd*gg.x + be.x);
  o[1] = (short)f2b(d1*rstd*gg.y + be.y);
  o[2] = (short)f2b(d2*rstd*gg.z + be.z);
  o[3] = (short)f2b(d3*rstd*gg.w + be.w);
  *(short4v*)(outB + base) = o;
}

// ---------------- GEMM: C[M][N] = A_bf16[M][K] @ BT_bf16[N][K]^T + bias ------------------
// Grid: blockIdx.x = m-tile (fast), blockIdx.y = n-tile — round-6 proven orientation.
// MODE 0: out bf16 ; MODE 1: relu -> bf16 ; MODE 2: + res(bf16) -> f32
// MODE 3: fused QKV: N=768, seg=n0>>8 -> 0: qb, 1: kb, 2: V granules (kv-PERMUTED)
// V granule layout (per 32-row kv block): granule g holds kv rows pi(g&1,j)+16*(g>>1),
// pi(h,j) = (j&3)+8*(j>>2)+4*h — matches the 32x32 MFMA C-layout register order so
// flash needs NO cross-lane P exchange. Inverse: u=kv&31 -> g=((u>>2)&1)|(((u>>4)&1)<<1),
// j=(u&3)|(((u>>3)&1)<<2). (HW-validated round 14)
template<int MODE>
__global__ void __launch_bounds__(256, 2) gemm_bt(const u16* __restrict__ A,
                                                  const u16* __restrict__ BT,
                                                  const float* __restrict__ bias,
                                                  const float* __restrict__ bias2,
                                                  const float* __restrict__ bias3,
                                                  const u16* __restrict__ res,
                                                  float* __restrict__ outF,
                                                  u16* __restrict__ outB,
                                                  u16* __restrict__ outB2,
                                                  u16* __restrict__ outB3,
                                                  int M, int N, int K){
  __shared__ u16 As[128*64];
  __shared__ u16 Bs[128*64];
  int tid = threadIdx.x;
  int m0 = blockIdx.x*128, n0 = blockIdx.y*128;
  int wave = tid>>6, lane = tid&63, lr = lane&15, lg = lane>>4;
  int wm = (wave>>1)*64, wn = (wave&1)*64;

  f32x4 acc[4][4];
  #pragma unroll
  for (int i=0;i<4;i++)
    #pragma unroll
    for (int j=0;j<4;j++) acc[i][j] = (f32x4){0.f,0.f,0.f,0.f};

  int nk = K >> 6;
  for (int kt=0; kt<nk; ++kt){
    __syncthreads();
    #pragma unroll
    for (int i=0;i<4;i++){
      int de = i*256 + tid; int row = de>>3; int ch = de&7; int sc = ch ^ (row&7);
      gload_lds16(A + (size_t)(m0+row)*K + kt*64 + sc*8, (char*)As + de*16);
    }
    #pragma unroll
    for (int i=0;i<4;i++){
      int de = i*256 + tid; int row = de>>3; int ch = de&7; int sc = ch ^ (row&7);
      gload_lds16(BT + (size_t)(n0+row)*K + kt*64 + sc*8, (char*)Bs + de*16);
    }
    asm volatile("s_waitcnt vmcnt(0)" ::: "memory");
    __syncthreads();
    #pragma unroll
    for (int kk=0;kk<2;kk++){
      short8 af[4], bf[4];
      #pragma unroll
      for (int mi=0;mi<4;mi++){
        int row = wm + mi*16 + lr;
        int c = (kk*4 + lg) ^ (row&7);
        af[mi] = *(const short8*)&As[row*64 + c*8];
      }
      #pragma unroll
      for (int ni=0;ni<4;ni++){
        int row = wn + ni*16 + lr;
        int c = (kk*4 + lg) ^ (row&7);
        bf[ni] = *(const short8*)&Bs[row*64 + c*8];
      }
      #pragma unroll
      for (int mi=0;mi<4;mi++)
        #pragma unroll
        for (int ni=0;ni<4;ni++)
          acc[mi][ni] = __builtin_amdgcn_mfma_f32_16x16x32_bf16(af[mi], bf[ni], acc[mi][ni], 0,0,0);
    }
  }
  #pragma unroll
  for (int mi=0;mi<4;mi++)
    #pragma unroll
    for (int ni=0;ni<4;ni++)
      #pragma unroll
      for (int r=0;r<4;r++){
        int row = m0 + wm + mi*16 + lg*4 + r;
        int col = n0 + wn + ni*16 + lr;
        if (MODE==3){
          int seg = n0 >> 8;
          int c2 = col & 255;
          float bb = (seg==0) ? bias[c2] : (seg==1) ? bias2[c2] : bias3[c2];
          float vout = acc[mi][ni][r] + bb;
          if (seg==0)      outB [(size_t)row*256 + c2] = f2b(vout);
          else if (seg==1) outB2[(size_t)row*256 + c2] = f2b(vout);
          else {
            // kv-permuted V granule: [b][gran][256 d][8 j]
            int n = row & 4095;
            int u = n & 31;
            int g = ((u>>2)&1) | (((u>>4)&1)<<1);
            int j = (u&3) | (((u>>3)&1)<<2);
            size_t gran = (size_t)((n>>5)<<2) + g;
            size_t gaddr = ((size_t)(row>>12)<<20) + (((gran<<8) + (size_t)c2)<<3) + j;
            outB3[gaddr] = f2b(vout);
          }
        } else {
          float vout = acc[mi][ni][r] + bias[col];
          if (MODE==1) vout = fmaxf(vout, 0.f);
          if (MODE==2) outF[(size_t)row*N + col] = vout + b2f(res[(size_t)row*N + col]);
          else         outB[(size_t)row*N + col] = f2b(vout);
        }
      }
}

// ------- Flash attention: K single-buffer (48 KB LDS -> 3 blocks/CU), V double -----------
// grid (32, B=4, SPLIT=4); block 256 (4 waves x 32 q-rows = 128 q / block).
// Q,K: [B*4096][256] bf16 ; Vt kv-permuted granules: [B][512][256][8] bf16.
// Opart: [split][B*4096][256] bf16 ; ML: [split][B*4096][2] f32.
// Schedule per iter t:  a) stage V(t+1)->V[(t+1)&1]   b) QKT(K)   c) barrier#1
//   d) stage K(t+1)->K   e) softmax+PV(V[t&1])   f) vmcnt(0); barrier#2
// Buffer audit: K write (d) vs prior read (b) sep by barrier#1; K write vs next
// read (t+1.b) sep by vmcnt(0)+barrier#2. V[(t+1)&1] write (a) drained at (f)
// before read (t+1.e); prior read (t-1.e) sep by (t-1.f) barrier.
__device__ __forceinline__ void stage_K(const u16* __restrict__ Kb,
                                        int b, int kv0, char* Kdst, int tid){
  #pragma unroll
  for (int i=0;i<4;i++){
    int de = i*256 + tid; int kv = de>>5; int c = de&31; int sc = c ^ (kv&7);
    gload_lds16(Kb + (((size_t)(b*4096 + kv0 + kv))<<8) + sc*8, Kdst + (size_t)de*16);
  }
}
__device__ __forceinline__ void stage_V(const u16* __restrict__ Vt,
                                        int b, int kv0, char* Vdst, int tid){
  #pragma unroll
  for (int i=0;i<4;i++){
    int de = i*256 + tid; int kvc = de>>8; int d = de&255;
    gload_lds16(Vt + ((((size_t)b*512 + (kv0>>3) + kvc)<<8) + (size_t)d)*8,
                Vdst + (size_t)de*16);
  }
}

__global__ void __launch_bounds__(256, 3) flash_attn32(const u16* __restrict__ Qb,
                                                       const u16* __restrict__ Kb,
                                                       const u16* __restrict__ Vt,
                                                       u16* __restrict__ Opart,
                                                       float* __restrict__ MLpart){
  // [K 16K][V0 16K][V1 16K] = 49152 -> 3 blocks/CU
  __shared__ __align__(16) char smem[49152];
  const int NC = 4096;
  int tid = threadIdx.x, wave = tid>>6, lane = tid&63;
  int lq = lane & 31, hi = lane >> 5;
  int b = blockIdx.y, s = blockIdx.z;
  int qb0 = blockIdx.x*128 + wave*32;
  int kvbeg = s*1024;
  const int NT = 32;
  char* Kc = smem;

  // Q B-frags in registers: lane holds Q[q = qb0+lq][ks*16 + hi*8 .. +7]
  short8 qf[16];
  {
    const u16* qbase = Qb + (((size_t)b*NC + qb0 + lq)<<8) + hi*8;
    #pragma unroll
    for (int ks=0; ks<16; ks++) qf[ks] = *(const short8*)(qbase + ks*16);
  }

  f32x16 o[8];
  #pragma unroll
  for (int i=0;i<8;i++)
    o[i] = (f32x16){0.f,0.f,0.f,0.f,0.f,0.f,0.f,0.f,0.f,0.f,0.f,0.f,0.f,0.f,0.f,0.f};
  float mrun = -__builtin_inff(), ell = 0.f;

  stage_K(Kb, b, kvbeg, Kc, tid);
  stage_V(Vt, b, kvbeg, smem + 16384, tid);
  asm volatile("s_waitcnt vmcnt(0)" ::: "memory");
  __syncthreads();

  for (int t=0; t<NT; t++){
    char* Vc = smem + 16384 + ((size_t)(t&1)<<14);
    char* Vn = smem + 16384 + ((size_t)((t+1)&1)<<14);
    if (t+1 < NT) stage_V(Vt, b, kvbeg + (t+1)*32, Vn, tid);            // (a)

    // ---- (b) S^T = K @ Q^T : lane holds S[q=lq][kv=(r&3)+8*(r>>2)+4*hi (+16 r>=8)] ----
    f32x16 sacc = (f32x16){0.f,0.f,0.f,0.f,0.f,0.f,0.f,0.f,0.f,0.f,0.f,0.f,0.f,0.f,0.f,0.f};
    __builtin_amdgcn_s_setprio(1);
    #pragma unroll
    for (int ks=0; ks<16; ks++){
      int c = ks*2 + hi;
      short8 kf = *(const short8*)(Kc + lq*512 + ((c ^ (lq&7))<<4));
      sacc = __builtin_amdgcn_mfma_f32_32x32x16_bf16(kf, qf[ks], sacc, 0,0,0);
    }
    __builtin_amdgcn_s_setprio(0);

    __syncthreads();                                                    // (c) all done with K
    if (t+1 < NT) stage_K(Kb, b, kvbeg + (t+1)*32, Kc, tid);            // (d)

    // ---- (e) online softmax, one q per lane (max via v_max3 fusion) ----
    float t0 = fmaxf(fmaxf(sacc[0], sacc[1]), sacc[2]);
    float t1 = fmaxf(fmaxf(sacc[3], sacc[4]), sacc[5]);
    float t2 = fmaxf(fmaxf(sacc[6], sacc[7]), sacc[8]);
    float t3 = fmaxf(fmaxf(sacc[9], sacc[10]), sacc[11]);
    float t4 = fmaxf(fmaxf(sacc[12], sacc[13]), sacc[14]);
    float tmax = fmaxf(fmaxf(fmaxf(t0, t1), t2), fmaxf(fmaxf(t3, t4), sacc[15]));
    tmax *= 0.0625f;
    tmax = fmaxf(tmax, __shfl_xor(tmax, 32));
    if (!__all(tmax <= mrun + 8.f)){           // T13 defer-max
      float mn = fmaxf(mrun, tmax);
      float sc = __expf(mrun - mn);
      mrun = mn; ell *= sc;
      #pragma unroll
      for (int r=0;r<16;r++){
        float scr = __shfl(sc, (r&3)+8*(r>>2)+4*hi);
        #pragma unroll
        for (int dt=0; dt<8; dt++) o[dt][r] *= scr;
      }
    }

    // ---- p + in-register P fragments (granule-matched; no LDS round-trip) ----
    float rs = 0.f;
    float pv[16];
    #pragma unroll
    for (int r=0;r<16;r++){ pv[r] = __expf(sacc[r]*0.0625f - mrun); rs += pv[r]; }
    rs += __shfl_xor(rs, 32);
    ell += rs;
    union { unsigned w[4]; short8 s; } c0, c1;
    #pragma unroll
    for (int r=0;r<4;r++){
      c0.w[r] = cvtpk_bf16(pv[2*r],   pv[2*r+1]);     // kv pi(hi,2r),pi(hi,2r+1)
      c1.w[r] = cvtpk_bf16(pv[8+2*r], pv[8+2*r+1]);   // +16
    }
    short8 pa0 = c0.s, pa1 = c1.s;

    // ---- O += P @ V (granule g holds kv pi(g&1,j)+16*(g>>1): slots agree) ----
    __builtin_amdgcn_s_setprio(1);
    #pragma unroll
    for (int dt=0; dt<8; dt++){
      short8 vf0 = *(const short8*)(Vc + (((hi  )*256 + dt*32 + lq)<<4));
      short8 vf1 = *(const short8*)(Vc + (((2+hi)*256 + dt*32 + lq)<<4));
      o[dt] = __builtin_amdgcn_mfma_f32_32x32x16_bf16(pa0, vf0, o[dt], 0,0,0);
      o[dt] = __builtin_amdgcn_mfma_f32_32x32x16_bf16(pa1, vf1, o[dt], 0,0,0);
    }
    __builtin_amdgcn_s_setprio(0);

    asm volatile("s_waitcnt vmcnt(0)" ::: "memory");                    // (f)
    __syncthreads();
  }

  // ---- write partials (bf16) ----
  size_t rowb = (size_t)s*16384 + (size_t)b*NC + qb0;
  #pragma unroll
  for (int dt=0; dt<8; dt++)
    #pragma unroll
    for (int r=0;r<16;r++){
      int q = (r&3) + 8*(r>>2) + 4*hi;
      Opart[(rowb + q)*256 + dt*32 + lq] = f2b(o[dt][r]);
    }
  if (lane < 32){
    MLpart[(rowb + lane)*2]     = mrun;
    MLpart[(rowb + lane)*2 + 1] = ell;
  }
}

// -- merge, wave-per-row: 4 rows/block, 4 elems/lane, shuffle-only LN2, no barriers -------
__global__ void __launch_bounds__(256) merge4_ln(const u16* __restrict__ Opart,
                                                 const float* __restrict__ MLpart,
                                                 const u16* __restrict__ xlnb,
                                                 const float* __restrict__ g2,
                                                 const float* __restrict__ be2,
                                                 u16* __restrict__ x2b,
                                                 u16* __restrict__ h2){
  int w = threadIdx.x >> 6, lane = threadIdx.x & 63;
  int row = blockIdx.x*4 + w;
  const size_t RS = 16384ull*256;
  float m[4], l[4];
  #pragma unroll
  for (int s=0;s<4;s++){
    m[s] = MLpart[((size_t)s*16384 + row)*2];
    l[s] = MLpart[((size_t)s*16384 + row)*2 + 1];
  }
  float M = fmaxf(fmaxf(m[0],m[1]), fmaxf(m[2],m[3]));
  float e[4]; float den = 0.f;
  #pragma unroll
  for (int s=0;s<4;s++){ e[s] = __expf(m[s]-M); den += l[s]*e[s]; }
  float inv = 1.0f/den;
  size_t idx = (size_t)row*256 + lane*4;
  float v[4] = {0.f,0.f,0.f,0.f};
  #pragma unroll
  for (int s=0;s<4;s++){
    short4v op = *(const short4v*)(Opart + (size_t)s*RS + idx);
    #pragma unroll
    for (int i=0;i<4;i++) v[i] += b2f((u16)op[i]) * e[s];
  }
  short4v xr = *(const short4v*)(xlnb + idx);
  #pragma unroll
  for (int i=0;i<4;i++) v[i] = v[i]*inv + b2f((u16)xr[i]);
  short4v xo;
  #pragma unroll
  for (int i=0;i<4;i++) xo[i] = (short)f2b(v[i]);
  *(short4v*)(x2b + idx) = xo;
  // ---- LN2, wave-local shuffle reduce ----
  float s1 = v[0]+v[1]+v[2]+v[3];
  #pragma unroll
  for (int mk=1; mk<64; mk<<=1) s1 += __shfl_xor(s1, mk);
  float mean = s1 * (1.0f/256.0f);
  float d[4]; float q = 0.f;
  #pragma unroll
  for (int i=0;i<4;i++){ d[i] = v[i]-mean; q += d[i]*d[i]; }
  #pragma unroll
  for (int mk=1; mk<64; mk<<=1) q += __shfl_xor(q, mk);
  float rstd = rsqrtf(q * (1.0f/256.0f) + 1e-5f);
  float4 gg = *(const float4*)(g2 + lane*4);
  float4 be = *(const float4*)(be2 + lane*4);
  short4v ho;
  ho[0] = (short)f2b(d[0]*rstd*gg.x + be.x);
  ho[1] = (short)f2b(d[1]*rstd*gg.y + be.y);
  ho[2] = (short)f2b(d[2]*rstd*gg.z + be.z);
  ho[3] = (short)f2b(d[3]*rstd*gg.w + be.w);
  *(short4v*)(h2 + idx) = ho;
}

extern "C" void kernel_launch(void* const* d_in, const int* in_sizes, int n_in,
                              void* d_out, int out_size, void* d_ws, size_t ws_size,
                              hipStream_t stream){
  const float* x   = (const float*)d_in[0];
  const float* g1  = (const float*)d_in[1];
  const float* be1 = (const float*)d_in[2];
  const float* wq  = (const float*)d_in[3];
  const float* bq  = (const float*)d_in[4];
  const float* wk  = (const float*)d_in[5];
  const float* bk  = (const float*)d_in[6];
  const float* wv  = (const float*)d_in[7];
  const float* bv  = (const float*)d_in[8];
  const float* g2  = (const float*)d_in[9];
  const float* be2 = (const float*)d_in[10];
  const float* w1  = (const float*)d_in[11];
  const float* bm1 = (const float*)d_in[12];
  const float* w2  = (const float*)d_in[13];
  const float* bm2 = (const float*)d_in[14];
  float* out = (float*)d_out;

  const size_t RS = 16384ull*256;
  char* p = (char*)d_ws;
  u16*  Op   = (u16*)p;    p += 4*RS*2;          // 32 MiB bf16 partials; reused as h1
  float* ML  = (float*)p;  p += 4*16384ull*2*4;  // 0.5 MiB
  u16* xb  = (u16*)p; p += RS*2;                 // 8 MiB (LN1 out, also merge residual)
  u16* qb  = (u16*)p; p += RS*2;                 // 8 MiB; reused as h2 after flash
  u16* kb  = (u16*)p; p += RS*2;
  u16* vT  = (u16*)p; p += RS*2;
  u16* x2b = (u16*)p; p += RS*2;                 // 8 MiB bf16 residual
  u16* wqkvT = (u16*)p; p += 3*65536ull*2;
  u16* w1T = (u16*)p; p += 262144ull*2;
  u16* w2T = (u16*)p; p += 262144ull*2;
  u16*   h1 = Op;
  u16*   h2 = qb;

  transpose_all<<<704, 256, 0, stream>>>(wq, wk, wv, w1, w2, wqkvT, w1T, w2T);

  ln_kernel<<<4096,256,0,stream>>>(x, g1, be1, xb);

  // fused QKV: qb, kb, kv-permuted V-granules in one GEMM
  gemm_bt<3><<<dim3(128,6),256,0,stream>>>(xb, wqkvT, bq, bk, bv, nullptr, nullptr,
                                           qb, kb, vT, 16384,768,256);

  flash_attn32<<<dim3(32,4,4),256,0,stream>>>(qb, kb, vT, Op, ML);
  merge4_ln<<<4096,256,0,stream>>>(Op, ML, xb, g2, be2, x2b, h2);

  gemm_bt<1><<<dim3(128,8),256,0,stream>>>(h2, w1T, bm1, nullptr, nullptr, nullptr, nullptr,
                                           h1, nullptr, nullptr, 16384,1024,256);
  gemm_bt<2><<<dim3(128,2),256,0,stream>>>(h1, w2T, bm2, nullptr, nullptr, x2b, out,
                                           nullptr, nullptr, nullptr, 16384,256,1024);
}

// Round 19
// 154.185 us; speedup vs baseline: 2.3449x; 2.3449x over previous
//
#include <hip/hip_runtime.h>
#include <stdint.h>

typedef unsigned short u16;
typedef __attribute__((ext_vector_type(8))) short short8;   // 8 x bf16 (4 VGPRs)
typedef __attribute__((ext_vector_type(4))) short short4v;  // 4 x bf16 (8B)
typedef __attribute__((ext_vector_type(4))) float f32x4;
typedef __attribute__((ext_vector_type(16))) float f32x16;

__device__ __forceinline__ u16 f2b(float f){
  union { float f; unsigned u; } x; x.f = f;
  unsigned r = x.u + 0x7FFFu + ((x.u >> 16) & 1u);  // RNE
  return (u16)(r >> 16);
}
__device__ __forceinline__ float b2f(u16 u){
  return __uint_as_float(((unsigned)u) << 16);
}

__device__ __forceinline__ unsigned cvtpk_bf16(float lo, float hi){
  unsigned r;
  asm("v_cvt_pk_bf16_f32 %0, %1, %2" : "=v"(r) : "v"(lo), "v"(hi));
  return r;
}

__device__ __forceinline__ void gload_lds16(const void* g, void* l){
  __builtin_amdgcn_global_load_lds(
      (const __attribute__((address_space(1))) unsigned int*)g,
      (__attribute__((address_space(3))) unsigned int*)l, 16, 0, 0);
}

// -------- all weight transposes in one kernel: 704 tile-jobs ----------------------------
__global__ void __launch_bounds__(256) transpose_all(const float* __restrict__ wq,
                                                     const float* __restrict__ wk,
                                                     const float* __restrict__ wv,
                                                     const float* __restrict__ w1,
                                                     const float* __restrict__ w2,
                                                     u16* __restrict__ wqkvT,
                                                     u16* __restrict__ w1T,
                                                     u16* __restrict__ w2T){
  __shared__ float sm[32][33];
  int id = blockIdx.x;
  const float* in; u16* out; int K, N, kx, ny;
  if (id < 192){
    int j = id >> 6, r = id & 63;
    in = (j==0) ? wq : (j==1) ? wk : wv;
    out = wqkvT + (size_t)j*65536; K = 256; N = 256; kx = r>>3; ny = r&7;
  } else if (id < 448){
    int r = id - 192; in = w1; out = w1T; K = 256; N = 1024; kx = r&7; ny = r>>3;
  } else {
    int r = id - 448; in = w2; out = w2T; K = 1024; N = 256; kx = r>>3; ny = r&7;
  }
  int k0 = kx*32, n0 = ny*32;
  int t = threadIdx.x; int tr = t>>5, tc = t&31;   // 8 x 32
  #pragma unroll
  for (int p=0;p<4;p++) sm[p*8+tr][tc] = in[(size_t)(k0+p*8+tr)*N + n0+tc];
  __syncthreads();
  #pragma unroll
  for (int p=0;p<4;p++) out[(size_t)(n0+p*8+tr)*K + k0+tc] = f2b(sm[tc][p*8+tr]);
}

// ------- LayerNorm, wave-per-row: 4 rows/block, 4 elems/lane, shuffle-only reduce --------
__global__ void __launch_bounds__(256) ln_kernel(const float* __restrict__ in,
                                                 const float* __restrict__ g,
                                                 const float* __restrict__ bb,
                                                 u16* __restrict__ outB){
  int w = threadIdx.x >> 6, lane = threadIdx.x & 63;
  int row = blockIdx.x*4 + w;
  size_t base = (size_t)row*256 + lane*4;
  float4 v = *(const float4*)(in + base);
  float s = v.x + v.y + v.z + v.w;
  #pragma unroll
  for (int mk=1; mk<64; mk<<=1) s += __shfl_xor(s, mk);
  float mean = s * (1.0f/256.0f);
  float d0 = v.x-mean, d1 = v.y-mean, d2 = v.z-mean, d3 = v.w-mean;
  float q = d0*d0 + d1*d1 + d2*d2 + d3*d3;
  #pragma unroll
  for (int mk=1; mk<64; mk<<=1) q += __shfl_xor(q, mk);
  float rstd = rsqrtf(q * (1.0f/256.0f) + 1e-5f);
  float4 gg = *(const float4*)(g + lane*4);
  float4 be = *(const float4*)(bb + lane*4);
  short4v o;
  o[0] = (short)f2b(d0*rstd*gg.x + be.x);
  o[1] = (short)f2b(d1*rstd*gg.y + be.y);
  o[2] = (short)f2b(d2*rstd*gg.z + be.z);
  o[3] = (short)f2b(d3*rstd*gg.w + be.w);
  *(short4v*)(outB + base) = o;
}

// ---------------- GEMM: C[M][N] = A_bf16[M][K] @ BT_bf16[N][K]^T + bias ------------------
// Grid: blockIdx.x = m-tile (fast), blockIdx.y = n-tile — round-6 proven orientation.
// MODE 0: out bf16 ; MODE 1: relu -> bf16 ; MODE 2: + res(bf16) -> f32
// MODE 3: fused QKV: N=768, seg=n0>>8 -> 0: qb, 1: kb, 2: V granules (kv-PERMUTED)
// V granule layout (per 32-row kv block): granule g holds kv rows pi(g&1,j)+16*(g>>1),
// pi(h,j) = (j&3)+8*(j>>2)+4*h — matches the 32x32 MFMA C-layout register order so
// flash needs NO cross-lane P exchange. Inverse: u=kv&31 -> g=((u>>2)&1)|(((u>>4)&1)<<1),
// j=(u&3)|(((u>>3)&1)<<2). (HW-validated round 14)
template<int MODE>
__global__ void __launch_bounds__(256, 2) gemm_bt(const u16* __restrict__ A,
                                                  const u16* __restrict__ BT,
                                                  const float* __restrict__ bias,
                                                  const float* __restrict__ bias2,
                                                  const float* __restrict__ bias3,
                                                  const u16* __restrict__ res,
                                                  float* __restrict__ outF,
                                                  u16* __restrict__ outB,
                                                  u16* __restrict__ outB2,
                                                  u16* __restrict__ outB3,
                                                  int M, int N, int K){
  __shared__ u16 As[128*64];
  __shared__ u16 Bs[128*64];
  int tid = threadIdx.x;
  int m0 = blockIdx.x*128, n0 = blockIdx.y*128;
  int wave = tid>>6, lane = tid&63, lr = lane&15, lg = lane>>4;
  int wm = (wave>>1)*64, wn = (wave&1)*64;

  f32x4 acc[4][4];
  #pragma unroll
  for (int i=0;i<4;i++)
    #pragma unroll
    for (int j=0;j<4;j++) acc[i][j] = (f32x4){0.f,0.f,0.f,0.f};

  int nk = K >> 6;
  for (int kt=0; kt<nk; ++kt){
    __syncthreads();
    #pragma unroll
    for (int i=0;i<4;i++){
      int de = i*256 + tid; int row = de>>3; int ch = de&7; int sc = ch ^ (row&7);
      gload_lds16(A + (size_t)(m0+row)*K + kt*64 + sc*8, (char*)As + de*16);
    }
    #pragma unroll
    for (int i=0;i<4;i++){
      int de = i*256 + tid; int row = de>>3; int ch = de&7; int sc = ch ^ (row&7);
      gload_lds16(BT + (size_t)(n0+row)*K + kt*64 + sc*8, (char*)Bs + de*16);
    }
    asm volatile("s_waitcnt vmcnt(0)" ::: "memory");
    __syncthreads();
    #pragma unroll
    for (int kk=0;kk<2;kk++){
      short8 af[4], bf[4];
      #pragma unroll
      for (int mi=0;mi<4;mi++){
        int row = wm + mi*16 + lr;
        int c = (kk*4 + lg) ^ (row&7);
        af[mi] = *(const short8*)&As[row*64 + c*8];
      }
      #pragma unroll
      for (int ni=0;ni<4;ni++){
        int row = wn + ni*16 + lr;
        int c = (kk*4 + lg) ^ (row&7);
        bf[ni] = *(const short8*)&Bs[row*64 + c*8];
      }
      #pragma unroll
      for (int mi=0;mi<4;mi++)
        #pragma unroll
        for (int ni=0;ni<4;ni++)
          acc[mi][ni] = __builtin_amdgcn_mfma_f32_16x16x32_bf16(af[mi], bf[ni], acc[mi][ni], 0,0,0);
    }
  }
  #pragma unroll
  for (int mi=0;mi<4;mi++)
    #pragma unroll
    for (int ni=0;ni<4;ni++)
      #pragma unroll
      for (int r=0;r<4;r++){
        int row = m0 + wm + mi*16 + lg*4 + r;
        int col = n0 + wn + ni*16 + lr;
        if (MODE==3){
          int seg = n0 >> 8;
          int c2 = col & 255;
          float bb = (seg==0) ? bias[c2] : (seg==1) ? bias2[c2] : bias3[c2];
          float vout = acc[mi][ni][r] + bb;
          if (seg==0)      outB [(size_t)row*256 + c2] = f2b(vout);
          else if (seg==1) outB2[(size_t)row*256 + c2] = f2b(vout);
          else {
            // kv-permuted V granule: [b][gran][256 d][8 j]
            int n = row & 4095;
            int u = n & 31;
            int g = ((u>>2)&1) | (((u>>4)&1)<<1);
            int j = (u&3) | (((u>>3)&1)<<2);
            size_t gran = (size_t)((n>>5)<<2) + g;
            size_t gaddr = ((size_t)(row>>12)<<20) + (((gran<<8) + (size_t)c2)<<3) + j;
            outB3[gaddr] = f2b(vout);
          }
        } else {
          float vout = acc[mi][ni][r] + bias[col];
          if (MODE==1) vout = fmaxf(vout, 0.f);
          if (MODE==2) outF[(size_t)row*N + col] = vout + b2f(res[(size_t)row*N + col]);
          else         outB[(size_t)row*N + col] = f2b(vout);
        }
      }
}

// ------- Flash attention: double-buffered K/V, in-register P (granule-matched V) ---------
// grid (32, B=4, SPLIT=4); block 256 (4 waves x 32 q-rows = 128 q / block).
// Q,K: [B*4096][256] bf16 ; Vt kv-permuted granules: [B][512][256][8] bf16.
// Opart: [split][B*4096][256] bf16 ; ML: [split][B*4096][2] f32.
// NOTE (round 18): VGPR-bound at 2 waves/SIMD (o[8]+qf[16] ~ 230 regs). Do NOT
// raise __launch_bounds__ min-waves: (256,3) caps VGPR -> accumulator spills to
// scratch (FETCH 75->744 MB, flash 84->293 us, measured).
__device__ __forceinline__ void stage_tiles(const u16* __restrict__ Kb,
                                            const u16* __restrict__ Vt,
                                            int b, int kv0,
                                            char* Kdst, char* Vdst, int tid){
  #pragma unroll
  for (int i=0;i<4;i++){
    int de = i*256 + tid; int kv = de>>5; int c = de&31; int sc = c ^ (kv&7);
    gload_lds16(Kb + (((size_t)(b*4096 + kv0 + kv))<<8) + sc*8, Kdst + (size_t)de*16);
  }
  #pragma unroll
  for (int i=0;i<4;i++){
    int de = i*256 + tid; int kvc = de>>8; int d = de&255;
    gload_lds16(Vt + ((((size_t)b*512 + (kv0>>3) + kvc)<<8) + (size_t)d)*8,
                Vdst + (size_t)de*16);
  }
}

__global__ void __launch_bounds__(256, 2) flash_attn32(const u16* __restrict__ Qb,
                                                       const u16* __restrict__ Kb,
                                                       const u16* __restrict__ Vt,
                                                       u16* __restrict__ Opart,
                                                       float* __restrict__ MLpart){
  // [K0 16K][V0 16K][K1 16K][V1 16K] = 65536
  __shared__ __align__(16) char smem[65536];
  const int NC = 4096;
  int tid = threadIdx.x, wave = tid>>6, lane = tid&63;
  int lq = lane & 31, hi = lane >> 5;
  int b = blockIdx.y, s = blockIdx.z;
  int qb0 = blockIdx.x*128 + wave*32;
  int kvbeg = s*1024;
  const int NT = 32;

  // Q B-frags in registers: lane holds Q[q = qb0+lq][ks*16 + hi*8 .. +7]
  short8 qf[16];
  {
    const u16* qbase = Qb + (((size_t)b*NC + qb0 + lq)<<8) + hi*8;
    #pragma unroll
    for (int ks=0; ks<16; ks++) qf[ks] = *(const short8*)(qbase + ks*16);
  }

  f32x16 o[8];
  #pragma unroll
  for (int i=0;i<8;i++)
    o[i] = (f32x16){0.f,0.f,0.f,0.f,0.f,0.f,0.f,0.f,0.f,0.f,0.f,0.f,0.f,0.f,0.f,0.f};
  float mrun = -__builtin_inff(), ell = 0.f;

  stage_tiles(Kb, Vt, b, kvbeg, smem, smem + 16384, tid);
  asm volatile("s_waitcnt vmcnt(0)" ::: "memory");
  __syncthreads();

  for (int t=0; t<NT; t++){
    char* Kc = smem + ((t&1) ? 32768 : 0);
    char* Vc = Kc + 16384;
    char* Kn = smem + ((t&1) ? 0 : 32768);
    char* Vn = Kn + 16384;
    int kv0 = kvbeg + t*32;
    if (t+1 < NT) stage_tiles(Kb, Vt, b, kv0+32, Kn, Vn, tid);

    // ---- S^T = K @ Q^T : lane holds S[q=lq][kv=(r&3)+8*(r>>2)+4*hi (+16 for r>=8)] ----
    f32x16 sacc = (f32x16){0.f,0.f,0.f,0.f,0.f,0.f,0.f,0.f,0.f,0.f,0.f,0.f,0.f,0.f,0.f,0.f};
    __builtin_amdgcn_s_setprio(1);
    #pragma unroll
    for (int ks=0; ks<16; ks++){
      int c = ks*2 + hi;
      short8 kf = *(const short8*)(Kc + lq*512 + ((c ^ (lq&7))<<4));
      sacc = __builtin_amdgcn_mfma_f32_32x32x16_bf16(kf, qf[ks], sacc, 0,0,0);
    }
    __builtin_amdgcn_s_setprio(0);

    // ---- online softmax, one q per lane (max via v_max3 fusion) ----
    float t0 = fmaxf(fmaxf(sacc[0], sacc[1]), sacc[2]);
    float t1 = fmaxf(fmaxf(sacc[3], sacc[4]), sacc[5]);
    float t2 = fmaxf(fmaxf(sacc[6], sacc[7]), sacc[8]);
    float t3 = fmaxf(fmaxf(sacc[9], sacc[10]), sacc[11]);
    float t4 = fmaxf(fmaxf(sacc[12], sacc[13]), sacc[14]);
    float tmax = fmaxf(fmaxf(fmaxf(t0, t1), t2), fmaxf(fmaxf(t3, t4), sacc[15]));
    tmax *= 0.0625f;
    tmax = fmaxf(tmax, __shfl_xor(tmax, 32));
    if (!__all(tmax <= mrun + 8.f)){           // T13 defer-max
      float mn = fmaxf(mrun, tmax);
      float sc = __expf(mrun - mn);
      mrun = mn; ell *= sc;
      #pragma unroll
      for (int r=0;r<16;r++){
        float scr = __shfl(sc, (r&3)+8*(r>>2)+4*hi);
        #pragma unroll
        for (int dt=0; dt<8; dt++) o[dt][r] *= scr;
      }
    }

    // ---- p + in-register P fragments (granule-matched; no LDS round-trip) ----
    float rs = 0.f;
    float pv[16];
    #pragma unroll
    for (int r=0;r<16;r++){ pv[r] = __expf(sacc[r]*0.0625f - mrun); rs += pv[r]; }
    rs += __shfl_xor(rs, 32);
    ell += rs;
    union { unsigned w[4]; short8 s; } c0, c1;
    #pragma unroll
    for (int r=0;r<4;r++){
      c0.w[r] = cvtpk_bf16(pv[2*r],   pv[2*r+1]);     // kv pi(hi,2r),pi(hi,2r+1)
      c1.w[r] = cvtpk_bf16(pv[8+2*r], pv[8+2*r+1]);   // +16
    }
    short8 pa0 = c0.s, pa1 = c1.s;

    // ---- O += P @ V (granule g holds kv pi(g&1,j)+16*(g>>1): slots agree) ----
    __builtin_amdgcn_s_setprio(1);
    #pragma unroll
    for (int dt=0; dt<8; dt++){
      short8 vf0 = *(const short8*)(Vc + (((hi  )*256 + dt*32 + lq)<<4));
      short8 vf1 = *(const short8*)(Vc + (((2+hi)*256 + dt*32 + lq)<<4));
      o[dt] = __builtin_amdgcn_mfma_f32_32x32x16_bf16(pa0, vf0, o[dt], 0,0,0);
      o[dt] = __builtin_amdgcn_mfma_f32_32x32x16_bf16(pa1, vf1, o[dt], 0,0,0);
    }
    __builtin_amdgcn_s_setprio(0);

    asm volatile("s_waitcnt vmcnt(0)" ::: "memory");
    __syncthreads();   // next tile staged + all waves done with cur
  }

  // ---- write partials (bf16) ----
  size_t rowb = (size_t)s*16384 + (size_t)b*NC + qb0;
  #pragma unroll
  for (int dt=0; dt<8; dt++)
    #pragma unroll
    for (int r=0;r<16;r++){
      int q = (r&3) + 8*(r>>2) + 4*hi;
      Opart[(rowb + q)*256 + dt*32 + lq] = f2b(o[dt][r]);
    }
  if (lane < 32){
    MLpart[(rowb + lane)*2]     = mrun;
    MLpart[(rowb + lane)*2 + 1] = ell;
  }
}

// -- merge, wave-per-row: 4 rows/block, 4 elems/lane, shuffle-only LN2, no barriers -------
__global__ void __launch_bounds__(256) merge4_ln(const u16* __restrict__ Opart,
                                                 const float* __restrict__ MLpart,
                                                 const u16* __restrict__ xlnb,
                                                 const float* __restrict__ g2,
                                                 const float* __restrict__ be2,
                                                 u16* __restrict__ x2b,
                                                 u16* __restrict__ h2){
  int w = threadIdx.x >> 6, lane = threadIdx.x & 63;
  int row = blockIdx.x*4 + w;
  const size_t RS = 16384ull*256;
  float m[4], l[4];
  #pragma unroll
  for (int s=0;s<4;s++){
    m[s] = MLpart[((size_t)s*16384 + row)*2];
    l[s] = MLpart[((size_t)s*16384 + row)*2 + 1];
  }
  float M = fmaxf(fmaxf(m[0],m[1]), fmaxf(m[2],m[3]));
  float e[4]; float den = 0.f;
  #pragma unroll
  for (int s=0;s<4;s++){ e[s] = __expf(m[s]-M); den += l[s]*e[s]; }
  float inv = 1.0f/den;
  size_t idx = (size_t)row*256 + lane*4;
  float v[4] = {0.f,0.f,0.f,0.f};
  #pragma unroll
  for (int s=0;s<4;s++){
    short4v op = *(const short4v*)(Opart + (size_t)s*RS + idx);
    #pragma unroll
    for (int i=0;i<4;i++) v[i] += b2f((u16)op[i]) * e[s];
  }
  short4v xr = *(const short4v*)(xlnb + idx);
  #pragma unroll
  for (int i=0;i<4;i++) v[i] = v[i]*inv + b2f((u16)xr[i]);
  short4v xo;
  #pragma unroll
  for (int i=0;i<4;i++) xo[i] = (short)f2b(v[i]);
  *(short4v*)(x2b + idx) = xo;
  // ---- LN2, wave-local shuffle reduce ----
  float s1 = v[0]+v[1]+v[2]+v[3];
  #pragma unroll
  for (int mk=1; mk<64; mk<<=1) s1 += __shfl_xor(s1, mk);
  float mean = s1 * (1.0f/256.0f);
  float d[4]; float q = 0.f;
  #pragma unroll
  for (int i=0;i<4;i++){ d[i] = v[i]-mean; q += d[i]*d[i]; }
  #pragma unroll
  for (int mk=1; mk<64; mk<<=1) q += __shfl_xor(q, mk);
  float rstd = rsqrtf(q * (1.0f/256.0f) + 1e-5f);
  float4 gg = *(const float4*)(g2 + lane*4);
  float4 be = *(const float4*)(be2 + lane*4);
  short4v ho;
  ho[0] = (short)f2b(d[0]*rstd*gg.x + be.x);
  ho[1] = (short)f2b(d[1]*rstd*gg.y + be.y);
  ho[2] = (short)f2b(d[2]*rstd*gg.z + be.z);
  ho[3] = (short)f2b(d[3]*rstd*gg.w + be.w);
  *(short4v*)(h2 + idx) = ho;
}

extern "C" void kernel_launch(void* const* d_in, const int* in_sizes, int n_in,
                              void* d_out, int out_size, void* d_ws, size_t ws_size,
                              hipStream_t stream){
  const float* x   = (const float*)d_in[0];
  const float* g1  = (const float*)d_in[1];
  const float* be1 = (const float*)d_in[2];
  const float* wq  = (const float*)d_in[3];
  const float* bq  = (const float*)d_in[4];
  const float* wk  = (const float*)d_in[5];
  const float* bk  = (const float*)d_in[6];
  const float* wv  = (const float*)d_in[7];
  const float* bv  = (const float*)d_in[8];
  const float* g2  = (const float*)d_in[9];
  const float* be2 = (const float*)d_in[10];
  const float* w1  = (const float*)d_in[11];
  const float* bm1 = (const float*)d_in[12];
  const float* w2  = (const float*)d_in[13];
  const float* bm2 = (const float*)d_in[14];
  float* out = (float*)d_out;

  const size_t RS = 16384ull*256;
  char* p = (char*)d_ws;
  u16*  Op   = (u16*)p;    p += 4*RS*2;          // 32 MiB bf16 partials; reused as h1
  float* ML  = (float*)p;  p += 4*16384ull*2*4;  // 0.5 MiB
  u16* xb  = (u16*)p; p += RS*2;                 // 8 MiB (LN1 out, also merge residual)
  u16* qb  = (u16*)p; p += RS*2;                 // 8 MiB; reused as h2 after flash
  u16* kb  = (u16*)p; p += RS*2;
  u16* vT  = (u16*)p; p += RS*2;
  u16* x2b = (u16*)p; p += RS*2;                 // 8 MiB bf16 residual
  u16* wqkvT = (u16*)p; p += 3*65536ull*2;
  u16* w1T = (u16*)p; p += 262144ull*2;
  u16* w2T = (u16*)p; p += 262144ull*2;
  u16*   h1 = Op;
  u16*   h2 = qb;

  transpose_all<<<704, 256, 0, stream>>>(wq, wk, wv, w1, w2, wqkvT, w1T, w2T);

  ln_kernel<<<4096,256,0,stream>>>(x, g1, be1, xb);

  // fused QKV: qb, kb, kv-permuted V-granules in one GEMM
  gemm_bt<3><<<dim3(128,6),256,0,stream>>>(xb, wqkvT, bq, bk, bv, nullptr, nullptr,
                                           qb, kb, vT, 16384,768,256);

  flash_attn32<<<dim3(32,4,4),256,0,stream>>>(qb, kb, vT, Op, ML);
  merge4_ln<<<4096,256,0,stream>>>(Op, ML, xb, g2, be2, x2b, h2);

  gemm_bt<1><<<dim3(128,8),256,0,stream>>>(h2, w1T, bm1, nullptr, nullptr, nullptr, nullptr,
                                           h1, nullptr, nullptr, 16384,1024,256);
  gemm_bt<2><<<dim3(128,2),256,0,stream>>>(h1, w2T, bm2, nullptr, nullptr, x2b, out,
                                           nullptr, nullptr, nullptr, 16384,256,1024);
}